// Round 9
// baseline (27.562 us; speedup 1.0000x reference)
//
#include <hip/hip_runtime.h>

constexpr int H  = 2048, W = 4096, HG = 16, WG = 32, BS = 128;
constexpr int S  = 2, Hs = H / S, Ws = W / S;
constexpr int TILE_R = 16, TILE_C = 128;    // raster tile (m-space): 256px x 32px
constexpr int LMAX = 1536;                  // per-tile culled list cap
constexpr int NB   = (Ws / TILE_C) * (Hs / TILE_R);   // 16*64 = 1024 blocks
constexpr unsigned long long MAGIC = 0x9E3779B97F4A7C15ULL;

#define AGT __HIP_MEMORY_SCOPE_AGENT
static __device__ __forceinline__ unsigned long long ld_u64(const unsigned long long* p) {
    return __hip_atomic_load(p, __ATOMIC_RELAXED, AGT);
}
static __device__ __forceinline__ void st_u64(unsigned long long* p, unsigned long long v) {
    __hip_atomic_store(p, v, __ATOMIC_RELAXED, AGT);
}

// Single dispatch, no init, XOR-tag publication (pk[2i]=payload, pk[2i+1]=payload^MAGIC).
// Work split: blocks 512..1023 run phase A (one box each); blocks 0..511 own the
// grid_ig cells. Every block rasters one 256x32-px tile; stores issue before grid_ig.
__global__ __launch_bounds__(256) void k_fused(
    const float* __restrict__ bc, const float* __restrict__ bp,
    int Nc, int Np,
    unsigned long long* __restrict__ pk,
    float* __restrict__ out)
{
    __shared__ int4  Lr[LMAX];
    __shared__ float Lw[LMAX];
    __shared__ unsigned long long pkl[512];
    __shared__ unsigned bits[16];
    __shared__ int cnt, s_iso;
    __shared__ float red_f[4];
    __shared__ int   red_j[4];

    int tid  = threadIdx.x;
    int lane = tid & 63, wv = tid >> 6;

    if (tid < 16) bits[tid] = 0u;
    if (tid == 0) { cnt = 0; s_iso = 0; }

    // ---------------- Phase A: box i on block 512+i ----------------
    int i = (int)blockIdx.x - 512;
    if (i >= 0 && i < Nc) {
        float x1 = bc[i*5+0], y1 = bc[i*5+1], x2 = bc[i*5+2], y2 = bc[i*5+3], sc = bc[i*5+4];
        float ax1 = (float)(int)(x1*0.5f), ay1 = (float)(int)(y1*0.5f);
        float ax2 = (float)(int)(x2*0.5f), ay2 = (float)(int)(y2*0.5f);
        float areaA = (ax2-ax1)*(ay2-ay1);

        // IoU argmax over prev boxes (numpy first-max tie-break)
        float bi = -1.0f; int bj = 0;
        for (int j = tid; j < Np; j += 256) {
            float bx1 = (float)(int)(bp[j*5+0]*0.5f), by1 = (float)(int)(bp[j*5+1]*0.5f);
            float bx2 = (float)(int)(bp[j*5+2]*0.5f), by2 = (float)(int)(bp[j*5+3]*0.5f);
            float ix1 = fmaxf(ax1,bx1), iy1 = fmaxf(ay1,by1);
            float ix2 = fminf(ax2,bx2), iy2 = fminf(ay2,by2);
            float inter = fmaxf(ix2-ix1,0.0f)*fmaxf(iy2-iy1,0.0f);
            float areaB = (bx2-bx1)*(by2-by1);
            float iou = inter/(areaA+areaB-inter);
            if (iou > bi || (iou == bi && j < bj)) { bi = iou; bj = j; }
        }
        #pragma unroll
        for (int off = 32; off; off >>= 1) {
            float oi = __shfl_xor(bi, off);
            int   oj = __shfl_xor(bj, off);
            if (oi > bi || (oi == bi && oj < bj)) { bi = oi; bj = oj; }
        }
        if (lane == 0) { red_f[wv] = bi; red_j[wv] = bj; }
        __syncthreads();
        bi = red_f[0]; bj = red_j[0];
        #pragma unroll
        for (int w2 = 1; w2 < 4; w2++) {
            float oi = red_f[w2]; int oj = red_j[w2];
            if (oi > bi || (oi == bi && oj < bj)) { bi = oi; bj = oj; }
        }
        bool m = bi > 0.0f;

        int gx1=(int)x1/BS, gy1=(int)y1/BS, gx2=((int)x2-1)/BS, gy2=((int)y2-1)/BS;
        float pjx1=bp[bj*5+0], pjy1=bp[bj*5+1], pjx2=bp[bj*5+2], pjy2=bp[bj*5+3];
        int hx1=(int)pjx1/BS, hy1=(int)pjy1/BS, hx2=((int)pjx2-1)/BS, hy2=((int)pjy2-1)/BS;

        // isolation vs all grid rects
        bool bad = false;
        int NT = Nc + Np;
        for (int k = tid; k < NT; k += 256) {
            const float* q = (k < Nc) ? &bc[(size_t)k*5] : &bp[(size_t)(k-Nc)*5];
            int qx1=(int)q[0]/BS, qy1=(int)q[1]/BS, qx2=((int)q[2]-1)/BS, qy2=((int)q[3]-1)/BS;
            bool ov = (gx1<=qx2)&&(qx1<=gx2)&&(gy1<=qy2)&&(qy1<=gy2);
            if (m) ov = ov || ((hx1<=qx2)&&(qx1<=hx2)&&(hy1<=qy2)&&(qy1<=hy2));
            bool excl = (k == i) || (m && k == Nc + bj);
            bad |= (ov && !excl);
        }
        if (__any(bad) && lane == 0) atomicOr(&s_iso, 1);
        __syncthreads();

        if (tid == 0) {
            bool big = ((int)y2 - (int)y1) >= 100;
            bool vc2 = (!s_iso && big && sc >= 0.7f);
            float ig = 1.0f - bi;
            unsigned hi = (unsigned)bj | (m ? 1u<<16 : 0u) | (vc2 ? 1u<<17 : 0u);
            unsigned long long payload = (unsigned long long)__float_as_uint(ig) |
                                         ((unsigned long long)hi << 32);
            st_u64(&pk[2*i], payload);
            asm volatile("s_waitcnt vmcnt(0)" ::: "memory");   // payload at MALL first
            st_u64(&pk[2*i+1], payload ^ MAGIC);
        }
    }
    __syncthreads();   // bits/cnt init visible; phase-A LDS reuse done

    // ------------- stage pk to LDS, XOR-link validated poll + bitmap -------------
    for (int r = tid; r < Nc; r += 256) {
        unsigned long long p, g;
        for (;;) {
            p = ld_u64(&pk[2*r]); g = ld_u64(&pk[2*r+1]);
            if ((p ^ g) == MAGIC) break;
            __builtin_amdgcn_s_sleep(8);
        }
        pkl[r] = p;
        unsigned hi = (unsigned)(p >> 32);
        if ((hi >> 16) & 1u) {
            unsigned bj = hi & 0xFFFFu;
            atomicOr(&bits[bj >> 5], 1u << (bj & 31));
        }
    }
    __syncthreads();

    // ---------------- cull rects vs this block's tile ----------------
    int tileb = blockIdx.x;
    int bx = (tileb & 15) * TILE_C;
    int by = (tileb >> 4) * TILE_R;
    int NT2 = 2*Nc + Np;
    for (int r = tid; r < NT2; r += 256) {
        int4 q; float w;
        if (r < Nc) {
            q = make_int4((int)(bc[r*5+0]*0.5f),(int)(bc[r*5+1]*0.5f),
                          (int)(bc[r*5+2]*0.5f),(int)(bc[r*5+3]*0.5f));
            w = __uint_as_float((unsigned)pkl[r]) * bc[r*5+4];
        } else if (r < 2*Nc) {
            int ii = r - Nc;
            unsigned long long v = pkl[ii];
            unsigned hi = (unsigned)(v >> 32);
            int bj = (int)(hi & 0xFFFFu);
            bool m = (hi >> 16) & 1u;
            q = make_int4((int)(bp[bj*5+0]*0.5f),(int)(bp[bj*5+1]*0.5f),
                          (int)(bp[bj*5+2]*0.5f),(int)(bp[bj*5+3]*0.5f));
            w = m ? __uint_as_float((unsigned)v) * bp[bj*5+4] : 0.0f;
        } else {
            int j = r - 2*Nc;
            bool mp = (bits[j >> 5] >> (j & 31)) & 1u;
            q = make_int4((int)(bp[j*5+0]*0.5f),(int)(bp[j*5+1]*0.5f),
                          (int)(bp[j*5+2]*0.5f),(int)(bp[j*5+3]*0.5f));
            w = mp ? 0.0f : bp[j*5+4];
        }
        if (w > 0.0f && q.x < bx+TILE_C && q.z > bx && q.y < by+TILE_R && q.w > by) {
            int idx = atomicAdd(&cnt, 1);
            if (idx < LMAX) { Lr[idx] = q; Lw[idx] = w; }
        }
    }
    __syncthreads();   // cnt + list final

    // ---------------- raster FIRST: per-pixel max + 2x2-upsampled stores ----------------
    {
        int n = min(cnt, LMAX);
        int tx = tid & 63;              // 64 col-groups * 2 m-cols = 128 m-cols
        int ty = tid >> 6;              // 4 row-groups * 4 rows   = 16 m-rows
        int c0 = bx + tx * 2;
        int r0 = by + ty * 4;
        float mv[4][2];
        #pragma unroll
        for (int rr = 0; rr < 4; rr++) { mv[rr][0] = 0.0f; mv[rr][1] = 0.0f; }
        for (int k = 0; k < n; k++) {
            int4 q = Lr[k];          // broadcast LDS read
            float w = Lw[k];
            bool cx0 = (c0     >= q.x) && (c0     < q.z);
            bool cx1 = (c0 + 1 >= q.x) && (c0 + 1 < q.z);
            #pragma unroll
            for (int rr = 0; rr < 4; rr++) {
                int y = r0 + rr;
                bool cy = (y >= q.y) && (y < q.w);
                if (cy && cx0) mv[rr][0] = fmaxf(mv[rr][0], w);
                if (cy && cx1) mv[rr][1] = fmaxf(mv[rr][1], w);
            }
        }
        #pragma unroll
        for (int rr = 0; rr < 4; rr++) {
            int y = r0 + rr;
            float4 v = make_float4(mv[rr][0], mv[rr][0], mv[rr][1], mv[rr][1]);
            *(float4*)&out[(size_t)(2*y)     * W + 2*c0] = v;   // 64 lanes -> 1KB row chunk
            *(float4*)&out[(size_t)(2*y + 1) * W + 2*c0] = v;
        }
    }

    // ---------------- grid_ig: blocks 0..HG*WG-1 each own one cell ----------------
    int last = -1;
    if (tileb < HG*WG) {
        int gy = tileb / WG, gx = tileb % WG;
        int NT = Nc + Np;
        for (int r = tid; r < NT; r += 256) {
            int4 q; bool act;
            if (r < Nc) {
                float cx1 = bc[r*5+0], cy1 = bc[r*5+1], cx2 = bc[r*5+2], cy2 = bc[r*5+3];
                int ggx1=(int)cx1/BS, ggy1=(int)cy1/BS, ggx2=((int)cx2-1)/BS, ggy2=((int)cy2-1)/BS;
                unsigned hi = (unsigned)(pkl[r] >> 32);
                if ((hi >> 16) & 1u) {
                    int bj = (int)(hi & 0xFFFFu);
                    int hx1=(int)bp[bj*5+0]/BS, hy1=(int)bp[bj*5+1]/BS;
                    int hx2=((int)bp[bj*5+2]-1)/BS, hy2=((int)bp[bj*5+3]-1)/BS;
                    q = make_int4(min(ggx1,hx1), min(ggy1,hy1), max(ggx2,hx2), max(ggy2,hy2));
                } else {
                    q = make_int4(ggx1,ggy1,ggx2,ggy2);
                }
                act = true;
            } else {
                int j = r - Nc;
                act = !((bits[j >> 5] >> (j & 31)) & 1u);
                q = make_int4((int)bp[j*5+0]/BS, (int)bp[j*5+1]/BS,
                              ((int)bp[j*5+2]-1)/BS, ((int)bp[j*5+3]-1)/BS);
            }
            if (act && gx >= q.x && gx <= q.z && gy >= q.y && gy <= q.w) last = r;
        }
        #pragma unroll
        for (int off = 32; off; off >>= 1) last = max(last, __shfl_xor(last, off));
        if (lane == 0) red_j[wv] = last;
    }
    __syncthreads();

    if (tileb < HG*WG && tid == 0) {
        int g = max(max(red_j[0], red_j[1]), max(red_j[2], red_j[3]));
        float gv = 0.0f;
        if (g >= 0) {
            if (g < Nc) gv = (((unsigned)(pkl[g] >> 32) >> 17) & 1u) ? 2.0f : 1.0f;
            else gv = 1.0f;
        }
        out[(size_t)H*W + tileb] = gv;
    }
}

extern "C" void kernel_launch(void* const* d_in, const int* in_sizes, int n_in,
                              void* d_out, int out_size, void* d_ws, size_t ws_size,
                              hipStream_t stream)
{
    const float* bc = (const float*)d_in[0];
    const float* bp = (const float*)d_in[1];
    int Nc = in_sizes[0] / 5;
    int Np = in_sizes[1] / 5;
    float* out = (float*)d_out;
    unsigned long long* pk = (unsigned long long*)d_ws;   // [2*Nc] payload/tag pairs

    k_fused<<<NB, 256, 0, stream>>>(bc, bp, Nc, Np, pk, out);
}

// Round 10
// 24.501 us; speedup vs baseline: 1.1249x; 1.1249x over previous
//
#include <hip/hip_runtime.h>

constexpr int H  = 2048, W = 4096, HG = 16, WG = 32, BS = 128;
constexpr int S  = 2, Hs = H / S, Ws = W / S;
constexpr int TILE_R = 32, TILE_C = 64;     // raster tile (m-space)
constexpr int LMAX = 1536;                  // per-tile culled list cap
constexpr int NB   = (Ws / TILE_C) * (Hs / TILE_R);   // 32*32 = 1024 blocks
constexpr unsigned long long MAGIC = 0x9E3779B97F4A7C15ULL;

#define AGT __HIP_MEMORY_SCOPE_AGENT
static __device__ __forceinline__ unsigned long long ld_u64(const unsigned long long* p) {
    return __hip_atomic_load(p, __ATOMIC_RELAXED, AGT);
}
static __device__ __forceinline__ void st_u64(unsigned long long* p, unsigned long long v) {
    __hip_atomic_store(p, v, __ATOMIC_RELAXED, AGT);
}

// Round-7 structure (single dispatch, no init, XOR-tag publication), with one
// change: raster+stores issue BEFORE grid_ig so the 33.5MB write burst starts
// earlier and grid_ig's scattered loads hide under the store drain.
__global__ __launch_bounds__(256) void k_fused(
    const float* __restrict__ bc, const float* __restrict__ bp,
    int Nc, int Np,
    unsigned long long* __restrict__ pk,
    float* __restrict__ out)
{
    __shared__ int4  Lr[LMAX];
    __shared__ float Lw[LMAX];
    __shared__ unsigned long long pkl[512];
    __shared__ unsigned bits[16];
    __shared__ int cnt, s_iso;
    __shared__ float red_f[4];
    __shared__ int   red_j[4];

    int tid  = threadIdx.x;
    int lane = tid & 63, wv = tid >> 6;

    // ---------------- Phase A: one box per block (blocks < Nc) ----------------
    int i = blockIdx.x;
    if (i < Nc) {
        float x1 = bc[i*5+0], y1 = bc[i*5+1], x2 = bc[i*5+2], y2 = bc[i*5+3], sc = bc[i*5+4];
        float ax1 = (float)(int)(x1*0.5f), ay1 = (float)(int)(y1*0.5f);
        float ax2 = (float)(int)(x2*0.5f), ay2 = (float)(int)(y2*0.5f);
        float areaA = (ax2-ax1)*(ay2-ay1);

        // IoU argmax over prev boxes (numpy first-max tie-break)
        float bi = -1.0f; int bj = 0;
        for (int j = tid; j < Np; j += 256) {
            float bx1 = (float)(int)(bp[j*5+0]*0.5f), by1 = (float)(int)(bp[j*5+1]*0.5f);
            float bx2 = (float)(int)(bp[j*5+2]*0.5f), by2 = (float)(int)(bp[j*5+3]*0.5f);
            float ix1 = fmaxf(ax1,bx1), iy1 = fmaxf(ay1,by1);
            float ix2 = fminf(ax2,bx2), iy2 = fminf(ay2,by2);
            float inter = fmaxf(ix2-ix1,0.0f)*fmaxf(iy2-iy1,0.0f);
            float areaB = (bx2-bx1)*(by2-by1);
            float iou = inter/(areaA+areaB-inter);
            if (iou > bi || (iou == bi && j < bj)) { bi = iou; bj = j; }
        }
        #pragma unroll
        for (int off = 32; off; off >>= 1) {
            float oi = __shfl_xor(bi, off);
            int   oj = __shfl_xor(bj, off);
            if (oi > bi || (oi == bi && oj < bj)) { bi = oi; bj = oj; }
        }
        if (tid == 0) s_iso = 0;
        if (lane == 0) { red_f[wv] = bi; red_j[wv] = bj; }
        __syncthreads();
        bi = red_f[0]; bj = red_j[0];
        #pragma unroll
        for (int w2 = 1; w2 < 4; w2++) {
            float oi = red_f[w2]; int oj = red_j[w2];
            if (oi > bi || (oi == bi && oj < bj)) { bi = oi; bj = oj; }
        }
        bool m = bi > 0.0f;

        int gx1=(int)x1/BS, gy1=(int)y1/BS, gx2=((int)x2-1)/BS, gy2=((int)y2-1)/BS;
        float pjx1=bp[bj*5+0], pjy1=bp[bj*5+1], pjx2=bp[bj*5+2], pjy2=bp[bj*5+3];
        int hx1=(int)pjx1/BS, hy1=(int)pjy1/BS, hx2=((int)pjx2-1)/BS, hy2=((int)pjy2-1)/BS;

        // isolation vs all grid rects
        bool bad = false;
        int NT = Nc + Np;
        for (int k = tid; k < NT; k += 256) {
            const float* q = (k < Nc) ? &bc[(size_t)k*5] : &bp[(size_t)(k-Nc)*5];
            int qx1=(int)q[0]/BS, qy1=(int)q[1]/BS, qx2=((int)q[2]-1)/BS, qy2=((int)q[3]-1)/BS;
            bool ov = (gx1<=qx2)&&(qx1<=gx2)&&(gy1<=qy2)&&(qy1<=gy2);
            if (m) ov = ov || ((hx1<=qx2)&&(qx1<=hx2)&&(hy1<=qy2)&&(qy1<=hy2));
            bool excl = (k == i) || (m && k == Nc + bj);
            bad |= (ov && !excl);
        }
        if (__any(bad) && lane == 0) atomicOr(&s_iso, 1);
        __syncthreads();

        if (tid == 0) {
            bool big = ((int)y2 - (int)y1) >= 100;
            bool vc2 = (!s_iso && big && sc >= 0.7f);
            float ig = 1.0f - bi;
            unsigned hi = (unsigned)bj | (m ? 1u<<16 : 0u) | (vc2 ? 1u<<17 : 0u);
            unsigned long long payload = (unsigned long long)__float_as_uint(ig) |
                                         ((unsigned long long)hi << 32);
            st_u64(&pk[2*i], payload);
            asm volatile("s_waitcnt vmcnt(0)" ::: "memory");   // payload at MALL first
            st_u64(&pk[2*i+1], payload ^ MAGIC);
        }
    }

    // ------------- stage pk to LDS, XOR-link validated poll + bitmap -------------
    if (tid < 16) bits[tid] = 0u;
    if (tid == 0) cnt = 0;
    __syncthreads();
    for (int r = tid; r < Nc; r += 256) {
        unsigned long long p, g;
        for (;;) {
            p = ld_u64(&pk[2*r]); g = ld_u64(&pk[2*r+1]);
            if ((p ^ g) == MAGIC) break;
            __builtin_amdgcn_s_sleep(8);
        }
        pkl[r] = p;
        unsigned hi = (unsigned)(p >> 32);
        if ((hi >> 16) & 1u) {
            unsigned bj = hi & 0xFFFFu;
            atomicOr(&bits[bj >> 5], 1u << (bj & 31));
        }
    }
    __syncthreads();

    // ---------------- cull rects vs this block's tile (64x32 m) ----------------
    int tileb = blockIdx.x;
    int bx = (tileb & 31) * TILE_C;
    int by = (tileb >> 5) * TILE_R;
    int NT2 = 2*Nc + Np;
    for (int r = tid; r < NT2; r += 256) {
        int4 q; float w;
        if (r < Nc) {
            q = make_int4((int)(bc[r*5+0]*0.5f),(int)(bc[r*5+1]*0.5f),
                          (int)(bc[r*5+2]*0.5f),(int)(bc[r*5+3]*0.5f));
            w = __uint_as_float((unsigned)pkl[r]) * bc[r*5+4];
        } else if (r < 2*Nc) {
            int ii = r - Nc;
            unsigned long long v = pkl[ii];
            unsigned hi = (unsigned)(v >> 32);
            int bj = (int)(hi & 0xFFFFu);
            bool m = (hi >> 16) & 1u;
            q = make_int4((int)(bp[bj*5+0]*0.5f),(int)(bp[bj*5+1]*0.5f),
                          (int)(bp[bj*5+2]*0.5f),(int)(bp[bj*5+3]*0.5f));
            w = m ? __uint_as_float((unsigned)v) * bp[bj*5+4] : 0.0f;
        } else {
            int j = r - 2*Nc;
            bool mp = (bits[j >> 5] >> (j & 31)) & 1u;
            q = make_int4((int)(bp[j*5+0]*0.5f),(int)(bp[j*5+1]*0.5f),
                          (int)(bp[j*5+2]*0.5f),(int)(bp[j*5+3]*0.5f));
            w = mp ? 0.0f : bp[j*5+4];
        }
        if (w > 0.0f && q.x < bx+TILE_C && q.z > bx && q.y < by+TILE_R && q.w > by) {
            int idx = atomicAdd(&cnt, 1);
            if (idx < LMAX) { Lr[idx] = q; Lw[idx] = w; }
        }
    }
    __syncthreads();   // cnt + list final

    // ---------------- raster FIRST: per-pixel max + 2x2-upsampled stores ----------------
    {
        int n = min(cnt, LMAX);
        int tx = tid & 31;
        int ty = tid >> 5;
        int c0 = bx + tx * 2;
        int r0 = by + ty * 4;
        float mv[4][2];
        #pragma unroll
        for (int rr = 0; rr < 4; rr++) { mv[rr][0] = 0.0f; mv[rr][1] = 0.0f; }
        for (int k = 0; k < n; k++) {
            int4 q = Lr[k];          // broadcast LDS read
            float w = Lw[k];
            bool cx0 = (c0     >= q.x) && (c0     < q.z);
            bool cx1 = (c0 + 1 >= q.x) && (c0 + 1 < q.z);
            #pragma unroll
            for (int rr = 0; rr < 4; rr++) {
                int y = r0 + rr;
                bool cy = (y >= q.y) && (y < q.w);
                if (cy && cx0) mv[rr][0] = fmaxf(mv[rr][0], w);
                if (cy && cx1) mv[rr][1] = fmaxf(mv[rr][1], w);
            }
        }
        #pragma unroll
        for (int rr = 0; rr < 4; rr++) {
            int y = r0 + rr;
            float4 v = make_float4(mv[rr][0], mv[rr][0], mv[rr][1], mv[rr][1]);
            *(float4*)&out[(size_t)(2*y)     * W + 2*c0] = v;
            *(float4*)&out[(size_t)(2*y + 1) * W + 2*c0] = v;
        }
    }

    // ---------------- grid_ig LAST: blocks 0..HG*WG-1 each own one cell ----------------
    int last = -1;
    if (tileb < HG*WG) {
        int gy = tileb / WG, gx = tileb % WG;
        int NT = Nc + Np;
        for (int r = tid; r < NT; r += 256) {
            int4 q; bool act;
            if (r < Nc) {
                float cx1 = bc[r*5+0], cy1 = bc[r*5+1], cx2 = bc[r*5+2], cy2 = bc[r*5+3];
                int ggx1=(int)cx1/BS, ggy1=(int)cy1/BS, ggx2=((int)cx2-1)/BS, ggy2=((int)cy2-1)/BS;
                unsigned hi = (unsigned)(pkl[r] >> 32);
                if ((hi >> 16) & 1u) {
                    int bj = (int)(hi & 0xFFFFu);
                    int hx1=(int)bp[bj*5+0]/BS, hy1=(int)bp[bj*5+1]/BS;
                    int hx2=((int)bp[bj*5+2]-1)/BS, hy2=((int)bp[bj*5+3]-1)/BS;
                    q = make_int4(min(ggx1,hx1), min(ggy1,hy1), max(ggx2,hx2), max(ggy2,hy2));
                } else {
                    q = make_int4(ggx1,ggy1,ggx2,ggy2);
                }
                act = true;
            } else {
                int j = r - Nc;
                act = !((bits[j >> 5] >> (j & 31)) & 1u);
                q = make_int4((int)bp[j*5+0]/BS, (int)bp[j*5+1]/BS,
                              ((int)bp[j*5+2]-1)/BS, ((int)bp[j*5+3]-1)/BS);
            }
            if (act && gx >= q.x && gx <= q.z && gy >= q.y && gy <= q.w) last = r;
        }
        #pragma unroll
        for (int off = 32; off; off >>= 1) last = max(last, __shfl_xor(last, off));
        if (lane == 0) red_j[wv] = last;
    }
    __syncthreads();

    if (tileb < HG*WG && tid == 0) {
        int g = max(max(red_j[0], red_j[1]), max(red_j[2], red_j[3]));
        float gv = 0.0f;
        if (g >= 0) {
            if (g < Nc) gv = (((unsigned)(pkl[g] >> 32) >> 17) & 1u) ? 2.0f : 1.0f;
            else gv = 1.0f;
        }
        out[(size_t)H*W + tileb] = gv;
    }
}

extern "C" void kernel_launch(void* const* d_in, const int* in_sizes, int n_in,
                              void* d_out, int out_size, void* d_ws, size_t ws_size,
                              hipStream_t stream)
{
    const float* bc = (const float*)d_in[0];
    const float* bp = (const float*)d_in[1];
    int Nc = in_sizes[0] / 5;
    int Np = in_sizes[1] / 5;
    float* out = (float*)d_out;
    unsigned long long* pk = (unsigned long long*)d_ws;   // [2*Nc] payload/tag pairs

    k_fused<<<NB, 256, 0, stream>>>(bc, bp, Nc, Np, pk, out);
}

// Round 11
// 22.983 us; speedup vs baseline: 1.1992x; 1.0661x over previous
//
#include <hip/hip_runtime.h>

constexpr int H  = 2048, W = 4096, HG = 16, WG = 32, BS = 128;
constexpr int S  = 2, Hs = H / S, Ws = W / S;
constexpr int TILE_R = 32, TILE_C = 64;     // raster tile (m-space)
constexpr int LMAX = 1536;                  // per-tile culled list cap
constexpr int NB   = (Ws / TILE_C) * (Hs / TILE_R);   // 32*32 = 1024 blocks
constexpr unsigned long long MAGIC = 0x9E3779B97F4A7C15ULL;

#define AGT __HIP_MEMORY_SCOPE_AGENT
static __device__ __forceinline__ unsigned long long ld_u64(const unsigned long long* p) {
    return __hip_atomic_load(p, __ATOMIC_RELAXED, AGT);
}
static __device__ __forceinline__ void st_u64(unsigned long long* p, unsigned long long v) {
    __hip_atomic_store(p, v, __ATOMIC_RELAXED, AGT);
}

// Single dispatch, no init, XOR-tag publication. Phase A publishes ONLY the
// IoU argmax result {ig, bj, m} (shortest possible pre-barrier chain).
// Isolation/val_c moved post-barrier into grid_ig blocks (one box each).
__global__ __launch_bounds__(256) void k_fused(
    const float* __restrict__ bc, const float* __restrict__ bp,
    int Nc, int Np,
    unsigned long long* __restrict__ pk,
    float* __restrict__ out)
{
    __shared__ int4  Lr[LMAX];
    __shared__ float Lw[LMAX];
    __shared__ unsigned long long pkl[512];
    __shared__ unsigned bits[16];
    __shared__ int cnt, s_iso, s_g;
    __shared__ float red_f[4];
    __shared__ int   red_j[4];

    int tid  = threadIdx.x;
    int lane = tid & 63, wv = tid >> 6;

    // ---------------- Phase A: IoU argmax only, one box per block ----------------
    int i = blockIdx.x;
    if (i < Nc) {
        float x1 = bc[i*5+0], y1 = bc[i*5+1], x2 = bc[i*5+2], y2 = bc[i*5+3];
        float ax1 = (float)(int)(x1*0.5f), ay1 = (float)(int)(y1*0.5f);
        float ax2 = (float)(int)(x2*0.5f), ay2 = (float)(int)(y2*0.5f);
        float areaA = (ax2-ax1)*(ay2-ay1);

        float bi = -1.0f; int bj = 0;
        for (int j = tid; j < Np; j += 256) {
            float bx1 = (float)(int)(bp[j*5+0]*0.5f), by1 = (float)(int)(bp[j*5+1]*0.5f);
            float bx2 = (float)(int)(bp[j*5+2]*0.5f), by2 = (float)(int)(bp[j*5+3]*0.5f);
            float ix1 = fmaxf(ax1,bx1), iy1 = fmaxf(ay1,by1);
            float ix2 = fminf(ax2,bx2), iy2 = fminf(ay2,by2);
            float inter = fmaxf(ix2-ix1,0.0f)*fmaxf(iy2-iy1,0.0f);
            float areaB = (bx2-bx1)*(by2-by1);
            float iou = inter/(areaA+areaB-inter);
            if (iou > bi || (iou == bi && j < bj)) { bi = iou; bj = j; }
        }
        #pragma unroll
        for (int off = 32; off; off >>= 1) {
            float oi = __shfl_xor(bi, off);
            int   oj = __shfl_xor(bj, off);
            if (oi > bi || (oi == bi && oj < bj)) { bi = oi; bj = oj; }
        }
        if (lane == 0) { red_f[wv] = bi; red_j[wv] = bj; }
        __syncthreads();
        if (tid == 0) {
            bi = red_f[0]; bj = red_j[0];
            #pragma unroll
            for (int w2 = 1; w2 < 4; w2++) {
                float oi = red_f[w2]; int oj = red_j[w2];
                if (oi > bi || (oi == bi && oj < bj)) { bi = oi; bj = oj; }
            }
            bool m = bi > 0.0f;
            float ig = 1.0f - bi;
            unsigned hi = (unsigned)bj | (m ? 1u<<16 : 0u);
            unsigned long long payload = (unsigned long long)__float_as_uint(ig) |
                                         ((unsigned long long)hi << 32);
            st_u64(&pk[2*i], payload);
            asm volatile("s_waitcnt vmcnt(0)" ::: "memory");   // payload at MALL first
            st_u64(&pk[2*i+1], payload ^ MAGIC);
        }
    }

    // ------------- stage pk to LDS, XOR-link validated poll + bitmap -------------
    if (tid < 16) bits[tid] = 0u;
    if (tid == 0) cnt = 0;
    __syncthreads();
    for (int r = tid; r < Nc; r += 256) {
        unsigned long long p, g;
        for (;;) {
            p = ld_u64(&pk[2*r]); g = ld_u64(&pk[2*r+1]);
            if ((p ^ g) == MAGIC) break;
            __builtin_amdgcn_s_sleep(8);
        }
        pkl[r] = p;
        unsigned hi = (unsigned)(p >> 32);
        if ((hi >> 16) & 1u) {
            unsigned bj = hi & 0xFFFFu;
            atomicOr(&bits[bj >> 5], 1u << (bj & 31));
        }
    }
    __syncthreads();

    // ---------------- cull rects vs this block's tile (64x32 m) ----------------
    int tileb = blockIdx.x;
    int bx = (tileb & 31) * TILE_C;
    int by = (tileb >> 5) * TILE_R;
    int NT2 = 2*Nc + Np;
    for (int r = tid; r < NT2; r += 256) {
        int4 q; float w;
        if (r < Nc) {
            q = make_int4((int)(bc[r*5+0]*0.5f),(int)(bc[r*5+1]*0.5f),
                          (int)(bc[r*5+2]*0.5f),(int)(bc[r*5+3]*0.5f));
            w = __uint_as_float((unsigned)pkl[r]) * bc[r*5+4];
        } else if (r < 2*Nc) {
            int ii = r - Nc;
            unsigned long long v = pkl[ii];
            unsigned hi = (unsigned)(v >> 32);
            int bj = (int)(hi & 0xFFFFu);
            bool m = (hi >> 16) & 1u;
            q = make_int4((int)(bp[bj*5+0]*0.5f),(int)(bp[bj*5+1]*0.5f),
                          (int)(bp[bj*5+2]*0.5f),(int)(bp[bj*5+3]*0.5f));
            w = m ? __uint_as_float((unsigned)v) * bp[bj*5+4] : 0.0f;
        } else {
            int j = r - 2*Nc;
            bool mp = (bits[j >> 5] >> (j & 31)) & 1u;
            q = make_int4((int)(bp[j*5+0]*0.5f),(int)(bp[j*5+1]*0.5f),
                          (int)(bp[j*5+2]*0.5f),(int)(bp[j*5+3]*0.5f));
            w = mp ? 0.0f : bp[j*5+4];
        }
        if (w > 0.0f && q.x < bx+TILE_C && q.z > bx && q.y < by+TILE_R && q.w > by) {
            int idx = atomicAdd(&cnt, 1);
            if (idx < LMAX) { Lr[idx] = q; Lw[idx] = w; }
        }
    }
    __syncthreads();   // cnt + list final

    // ---------------- raster: per-pixel max + 2x2-upsampled stores ----------------
    {
        int n = min(cnt, LMAX);
        int tx = tid & 31;
        int ty = tid >> 5;
        int c0 = bx + tx * 2;
        int r0 = by + ty * 4;
        float mv[4][2];
        #pragma unroll
        for (int rr = 0; rr < 4; rr++) { mv[rr][0] = 0.0f; mv[rr][1] = 0.0f; }
        for (int k = 0; k < n; k++) {
            int4 q = Lr[k];          // broadcast LDS read
            float w = Lw[k];
            bool cx0 = (c0     >= q.x) && (c0     < q.z);
            bool cx1 = (c0 + 1 >= q.x) && (c0 + 1 < q.z);
            #pragma unroll
            for (int rr = 0; rr < 4; rr++) {
                int y = r0 + rr;
                bool cy = (y >= q.y) && (y < q.w);
                if (cy && cx0) mv[rr][0] = fmaxf(mv[rr][0], w);
                if (cy && cx1) mv[rr][1] = fmaxf(mv[rr][1], w);
            }
        }
        #pragma unroll
        for (int rr = 0; rr < 4; rr++) {
            int y = r0 + rr;
            float4 v = make_float4(mv[rr][0], mv[rr][0], mv[rr][1], mv[rr][1]);
            *(float4*)&out[(size_t)(2*y)     * W + 2*c0] = v;
            *(float4*)&out[(size_t)(2*y + 1) * W + 2*c0] = v;
        }
    }

    // -------- grid_ig (blocks 0..511): find last cover, then isolation for it --------
    if (tileb < HG*WG) {
        int gy = tileb / WG, gx = tileb % WG;
        int NT = Nc + Np;
        int last = -1;
        for (int r = tid; r < NT; r += 256) {
            int4 q; bool act;
            if (r < Nc) {
                float cx1 = bc[r*5+0], cy1 = bc[r*5+1], cx2 = bc[r*5+2], cy2 = bc[r*5+3];
                int ggx1=(int)cx1/BS, ggy1=(int)cy1/BS, ggx2=((int)cx2-1)/BS, ggy2=((int)cy2-1)/BS;
                unsigned hi = (unsigned)(pkl[r] >> 32);
                if ((hi >> 16) & 1u) {
                    int bj = (int)(hi & 0xFFFFu);
                    int hx1=(int)bp[bj*5+0]/BS, hy1=(int)bp[bj*5+1]/BS;
                    int hx2=((int)bp[bj*5+2]-1)/BS, hy2=((int)bp[bj*5+3]-1)/BS;
                    q = make_int4(min(ggx1,hx1), min(ggy1,hy1), max(ggx2,hx2), max(ggy2,hy2));
                } else {
                    q = make_int4(ggx1,ggy1,ggx2,ggy2);
                }
                act = true;
            } else {
                int j = r - Nc;
                act = !((bits[j >> 5] >> (j & 31)) & 1u);
                q = make_int4((int)bp[j*5+0]/BS, (int)bp[j*5+1]/BS,
                              ((int)bp[j*5+2]-1)/BS, ((int)bp[j*5+3]-1)/BS);
            }
            if (act && gx >= q.x && gx <= q.z && gy >= q.y && gy <= q.w) last = r;
        }
        #pragma unroll
        for (int off = 32; off; off >>= 1) last = max(last, __shfl_xor(last, off));
        if (lane == 0) red_j[wv] = last;
        __syncthreads();
        if (tid == 0) {
            s_g = max(max(red_j[0], red_j[1]), max(red_j[2], red_j[3]));
            s_iso = 0;
        }
        __syncthreads();
        int g = s_g;
        if (g >= 0 && g < Nc) {
            // isolation test for box g only (block-uniform g)
            float x1 = bc[g*5+0], y1 = bc[g*5+1], x2 = bc[g*5+2], y2 = bc[g*5+3];
            int gx1=(int)x1/BS, gy1=(int)y1/BS, gx2=((int)x2-1)/BS, gy2=((int)y2-1)/BS;
            unsigned hi = (unsigned)(pkl[g] >> 32);
            bool m = (hi >> 16) & 1u;
            int bj = (int)(hi & 0xFFFFu);
            int hx1=(int)bp[bj*5+0]/BS, hy1=(int)bp[bj*5+1]/BS;
            int hx2=((int)bp[bj*5+2]-1)/BS, hy2=((int)bp[bj*5+3]-1)/BS;
            bool bad = false;
            int NTk = Nc + Np;
            for (int k = tid; k < NTk; k += 256) {
                const float* q = (k < Nc) ? &bc[(size_t)k*5] : &bp[(size_t)(k-Nc)*5];
                int qx1=(int)q[0]/BS, qy1=(int)q[1]/BS, qx2=((int)q[2]-1)/BS, qy2=((int)q[3]-1)/BS;
                bool ov = (gx1<=qx2)&&(qx1<=gx2)&&(gy1<=qy2)&&(qy1<=gy2);
                if (m) ov = ov || ((hx1<=qx2)&&(qx1<=hx2)&&(hy1<=qy2)&&(qy1<=hy2));
                bool excl = (k == g) || (m && k == Nc + bj);
                bad |= (ov && !excl);
            }
            if (__any(bad) && lane == 0) atomicOr(&s_iso, 1);
            __syncthreads();
            if (tid == 0) {
                bool big = ((int)y2 - (int)y1) >= 100;
                float sc = bc[g*5+4];
                out[(size_t)H*W + tileb] = (!s_iso && big && sc >= 0.7f) ? 2.0f : 1.0f;
            }
        } else if (tid == 0) {
            out[(size_t)H*W + tileb] = (g >= Nc) ? 1.0f : 0.0f;
        }
    }
}

extern "C" void kernel_launch(void* const* d_in, const int* in_sizes, int n_in,
                              void* d_out, int out_size, void* d_ws, size_t ws_size,
                              hipStream_t stream)
{
    const float* bc = (const float*)d_in[0];
    const float* bp = (const float*)d_in[1];
    int Nc = in_sizes[0] / 5;
    int Np = in_sizes[1] / 5;
    float* out = (float*)d_out;
    unsigned long long* pk = (unsigned long long*)d_ws;   // [2*Nc] payload/tag pairs

    k_fused<<<NB, 256, 0, stream>>>(bc, bp, Nc, Np, pk, out);
}